// Round 4
// baseline (376.164 us; speedup 1.0000x reference)
//
#include <hip/hip_runtime.h>
#include <stdint.h>

#define SEQ   2048
#define DMODEL 2048
#define NQH   32
#define NKVH  8
#define HDIM  64
#define QN    (NQH*HDIM)    // 2048
#define KVNN  (NKVH*HDIM)   // 512

typedef __bf16 bf16x8 __attribute__((ext_vector_type(8)));
typedef float  f32x4  __attribute__((ext_vector_type(4)));
typedef unsigned short u16;

__device__ __forceinline__ u16 f2bf(float f) {
  uint32_t u = __builtin_bit_cast(uint32_t, f);
  u += 0x7fffu + ((u >> 16) & 1u);   // RNE
  return (u16)(u >> 16);
}
__device__ __forceinline__ float bf2f(u16 b) {
  return __builtin_bit_cast(float, (uint32_t)b << 16);
}

// Probe: first 32-bit word of the cos buffer. cos[0][0][0]=cos(0)=1.0 and (bf16
// case) cos[0][0][1]=1.0 too. f32 -> 0x3F800000 (low16==0); bf16 -> 0x3F803F80.
__device__ __forceinline__ bool probe_is_f32(const uint32_t* p) {
  return (p[0] & 0xFFFFu) == 0u;
}

// ---------------------------------------------------------------------------
// Fused input conversion: all 7 inputs -> bf16 copies in ws.
// Each thread handles 8 elements. Segments (8-elt units, compile-time):
//   X 524288 | wq 524288 | wk 131072 | wv 131072 | wo 524288 | cos 16384 | sin 16384
// ---------------------------------------------------------------------------
__global__ __launch_bounds__(256)
void conv_all(const void* __restrict__ X, const void* __restrict__ cosv,
              const void* __restrict__ sinv, const void* __restrict__ wq,
              const void* __restrict__ wk, const void* __restrict__ wv,
              const void* __restrict__ wo,
              u16* __restrict__ Xc, u16* __restrict__ cosc, u16* __restrict__ sinc,
              u16* __restrict__ wqc, u16* __restrict__ wkc, u16* __restrict__ wvc,
              u16* __restrict__ woc)
{
  const bool f32in = probe_is_f32((const uint32_t*)cosv);
  const long t = (long)blockIdx.x * 256 + threadIdx.x;
  const void* src; u16* dst; long off;
  if      (t < 524288L)  { src = X;    dst = Xc;   off = t; }
  else if (t < 1048576L) { src = wq;   dst = wqc;  off = t - 524288L; }
  else if (t < 1179648L) { src = wk;   dst = wkc;  off = t - 1048576L; }
  else if (t < 1310720L) { src = wv;   dst = wvc;  off = t - 1179648L; }
  else if (t < 1835008L) { src = wo;   dst = woc;  off = t - 1310720L; }
  else if (t < 1851392L) { src = cosv; dst = cosc; off = t - 1835008L; }
  else                   { src = sinv; dst = sinc; off = t - 1851392L; }
  if (f32in) {
    const float4* s = (const float4*)src;
    float4 a = s[2*off], b = s[2*off + 1];
    union { u16 h[8]; uint4 u; } o;
    o.h[0]=f2bf(a.x); o.h[1]=f2bf(a.y); o.h[2]=f2bf(a.z); o.h[3]=f2bf(a.w);
    o.h[4]=f2bf(b.x); o.h[5]=f2bf(b.y); o.h[6]=f2bf(b.z); o.h[7]=f2bf(b.w);
    *(uint4*)(dst + off*8) = o.u;
  } else {
    *(uint4*)(dst + off*8) = ((const uint4*)src)[off];
  }
}

// ---------------------------------------------------------------------------
// C[M][N] = A[M][K] @ B[N][K]^T, bf16 in, fp32 accum. 128x128 tile, BK=32.
// Output bf16, or f32 when outprobe says the true buffers are f32.
// ---------------------------------------------------------------------------
__global__ __launch_bounds__(256, 2)
void gemm_nt(const u16* __restrict__ A, const u16* __restrict__ B,
             void* __restrict__ C, int M, int N, int K,
             const uint32_t* outprobe)
{
  __shared__ __align__(16) u16 As[128][40];   // +8 pad: row stride 80B = 5*16B
  __shared__ __align__(16) u16 Bs[128][40];
  const int tid  = threadIdx.x;
  const int wave = tid >> 6;
  const int lane = tid & 63;
  const int quad = lane >> 4;
  const int l16  = lane & 15;
  const int m0 = blockIdx.y * 128;
  const int n0 = blockIdx.x * 128;
  const int wm = (wave >> 1) * 64;
  const int wn = (wave & 1) * 64;
  const int srow = tid >> 2;        // 0..63, 4 threads/row
  const int scol = (tid & 3) * 8;   // 8 bf16 = 16B per thread

  f32x4 acc[4][4];
  #pragma unroll
  for (int i = 0; i < 4; i++)
    #pragma unroll
    for (int j = 0; j < 4; j++)
      acc[i][j] = (f32x4){0.f, 0.f, 0.f, 0.f};

  for (int k0 = 0; k0 < K; k0 += 32) {
    uint4 a0 = *(const uint4*)(A + (size_t)(m0 + srow)      * K + k0 + scol);
    uint4 a1 = *(const uint4*)(A + (size_t)(m0 + srow + 64) * K + k0 + scol);
    uint4 b0 = *(const uint4*)(B + (size_t)(n0 + srow)      * K + k0 + scol);
    uint4 b1 = *(const uint4*)(B + (size_t)(n0 + srow + 64) * K + k0 + scol);
    __syncthreads();                       // prev iter done reading LDS
    *(uint4*)&As[srow][scol]      = a0;
    *(uint4*)&As[srow + 64][scol] = a1;
    *(uint4*)&Bs[srow][scol]      = b0;
    *(uint4*)&Bs[srow + 64][scol] = b1;
    __syncthreads();
    bf16x8 af[4], bfr[4];
    #pragma unroll
    for (int i = 0; i < 4; i++) af[i]  = *(const bf16x8*)&As[wm + i*16 + l16][quad*8];
    #pragma unroll
    for (int j = 0; j < 4; j++) bfr[j] = *(const bf16x8*)&Bs[wn + j*16 + l16][quad*8];
    #pragma unroll
    for (int i = 0; i < 4; i++)
      #pragma unroll
      for (int j = 0; j < 4; j++)
        acc[i][j] = __builtin_amdgcn_mfma_f32_16x16x32_bf16(af[i], bfr[j], acc[i][j], 0, 0, 0);
  }

  const bool f32out = (outprobe != nullptr) && probe_is_f32(outprobe);
  // C/D layout: col = lane&15, row = quad*4 + r   [verified m89/m91]
  #pragma unroll
  for (int i = 0; i < 4; i++) {
    const int rb = m0 + wm + i*16 + quad*4;
    #pragma unroll
    for (int j = 0; j < 4; j++) {
      const int col = n0 + wn + j*16 + l16;
      if (f32out) {
        float* Cf = (float*)C;
        #pragma unroll
        for (int r = 0; r < 4; r++)
          Cf[(size_t)(rb + r) * N + col] = acc[i][j][r];
      } else {
        u16* Ch = (u16*)C;
        #pragma unroll
        for (int r = 0; r < 4; r++)
          Ch[(size_t)(rb + r) * N + col] = f2bf(acc[i][j][r]);
      }
    }
  }
}

// ---------------------------------------------------------------------------
// RoPE in-place on Q [SEQ][2048] and K [SEQ][512]; Q additionally scaled 1/8.
// ---------------------------------------------------------------------------
__global__ void rope_kernel(u16* __restrict__ Qb, u16* __restrict__ Kb,
                            const u16* __restrict__ cosb, const u16* __restrict__ sinb)
{
  const int idx = blockIdx.x * 256 + threadIdx.x;
  const int qtotal = SEQ * NQH * 32;   // 2,097,152
  u16* base;
  int s, d;
  float scale;
  if (idx < qtotal) {
    s = idx >> 10;                 // /(32 heads * 32 d)
    const int rem = idx & 1023;
    base = Qb + (size_t)s * QN + (rem >> 5) * 64;
    d = rem & 31;
    scale = 0.125f;                // attention scale folded in (exact pow2)
  } else {
    const int t = idx - qtotal;
    s = t >> 8;                    // /(8 heads * 32 d)
    const int rem = t & 255;
    base = Kb + (size_t)s * KVNN + (rem >> 5) * 64;
    d = rem & 31;
    scale = 1.0f;
  }
  const float x1 = bf2f(base[d]);
  const float x2 = bf2f(base[d + 32]);
  const float c1 = bf2f(cosb[s * 64 + d]);
  const float c2 = bf2f(cosb[s * 64 + d + 32]);
  const float s1 = bf2f(sinb[s * 64 + d]);
  const float s2 = bf2f(sinb[s * 64 + d + 32]);
  base[d]      = f2bf((x1 * c1 - x2 * s1) * scale);
  base[d + 32] = f2bf((x2 * c2 + x1 * s2) * scale);
}

// ---------------------------------------------------------------------------
// Causal GQA flash attention. Block = (head h, 128-row Q tile). 4 waves,
// each wave owns 32 Q rows. K-tile = 64 keys. Online softmax per row.
// ---------------------------------------------------------------------------
__device__ __forceinline__ float qmax16(float v) {
  v = fmaxf(v, __shfl_xor(v, 1)); v = fmaxf(v, __shfl_xor(v, 2));
  v = fmaxf(v, __shfl_xor(v, 4)); v = fmaxf(v, __shfl_xor(v, 8));
  return v;
}
__device__ __forceinline__ float qsum16(float v) {
  v += __shfl_xor(v, 1); v += __shfl_xor(v, 2);
  v += __shfl_xor(v, 4); v += __shfl_xor(v, 8);
  return v;
}

__global__ __launch_bounds__(256, 2)
void attn_kernel(const u16* __restrict__ Qb,   // [SEQ][2048] (RoPE'd, pre-scaled)
                 const u16* __restrict__ Kb,   // [SEQ][512]  (RoPE'd)
                 const u16* __restrict__ Vb,   // [SEQ][512]
                 u16* __restrict__ Ob)         // [SEQ][2048]
{
  const int h   = blockIdx.x;       // 0..31
  const int qt  = blockIdx.y;       // 0..15
  const int hkv = h >> 2;           // GROUPS = 4
  __shared__ __align__(16) u16 Ks[64][72];        // [key][d]  stride 144B = 9*16B
  __shared__ __align__(16) u16 Vt[64][72];        // [d][key]  (transposed at staging)
  __shared__ __align__(16) u16 Ps[4][32][72];     // per-wave P round-trip

  const int tid  = threadIdx.x;
  const int wave = tid >> 6;
  const int lane = tid & 63;
  const int quad = lane >> 4;
  const int l16  = lane & 15;
  const int qrow0 = qt * 128 + wave * 32;   // wave's first global q row

  // Q fragments (A-operand layout: m = lane&15, k = quad*8+j) loaded once
  bf16x8 qf[2][2];
  #pragma unroll
  for (int mt = 0; mt < 2; mt++)
    #pragma unroll
    for (int ks = 0; ks < 2; ks++)
      qf[mt][ks] = *(const bf16x8*)(Qb + (size_t)(qrow0 + mt*16 + l16) * QN
                                       + h*64 + ks*32 + quad*8);

  f32x4 oacc[2][4];
  #pragma unroll
  for (int mt = 0; mt < 2; mt++)
    #pragma unroll
    for (int nt = 0; nt < 4; nt++)
      oacc[mt][nt] = (f32x4){0.f, 0.f, 0.f, 0.f};
  float m_run[2][4], l_run[2][4];
  #pragma unroll
  for (int mt = 0; mt < 2; mt++)
    #pragma unroll
    for (int r = 0; r < 4; r++) { m_run[mt][r] = -1e30f; l_run[mt][r] = 0.f; }

  const int sr = tid >> 3;          // 0..31
  const int sc = (tid & 7) * 8;     // 0..56
  const int ktmax = 2 * qt + 2;

  for (int kt = 0; kt < ktmax; kt++) {
    const int kb = kt * 64;
    // ---- stage K (row-major) and V (transposed) ----
    union { uint4 u; u16 h[8]; } kv0, kv1, vv0, vv1;
    kv0.u = *(const uint4*)(Kb + (size_t)(kb + sr)      * KVNN + hkv*64 + sc);
    kv1.u = *(const uint4*)(Kb + (size_t)(kb + sr + 32) * KVNN + hkv*64 + sc);
    vv0.u = *(const uint4*)(Vb + (size_t)(kb + sr)      * KVNN + hkv*64 + sc);
    vv1.u = *(const uint4*)(Vb + (size_t)(kb + sr + 32) * KVNN + hkv*64 + sc);
    __syncthreads();
    *(uint4*)&Ks[sr][sc]      = kv0.u;
    *(uint4*)&Ks[sr + 32][sc] = kv1.u;
    #pragma unroll
    for (int j = 0; j < 8; j++) { Vt[sc + j][sr] = vv0.h[j]; Vt[sc + j][sr + 32] = vv1.h[j]; }
    __syncthreads();

    // waves 0,1 are fully masked in the second diagonal tile -> skip compute
    const bool skip = (kt == 2*qt + 1) && (wave < 2);
    if (!skip) {
      // ---- S = Q @ K^T ----
      f32x4 sacc[2][4];
      #pragma unroll
      for (int mt = 0; mt < 2; mt++)
        #pragma unroll
        for (int nt = 0; nt < 4; nt++)
          sacc[mt][nt] = (f32x4){0.f, 0.f, 0.f, 0.f};
      #pragma unroll
      for (int ks = 0; ks < 2; ks++)
        #pragma unroll
        for (int nt = 0; nt < 4; nt++) {
          bf16x8 kf = *(const bf16x8*)&Ks[nt*16 + l16][ks*32 + quad*8];
          sacc[0][nt] = __builtin_amdgcn_mfma_f32_16x16x32_bf16(qf[0][ks], kf, sacc[0][nt], 0,0,0);
          sacc[1][nt] = __builtin_amdgcn_mfma_f32_16x16x32_bf16(qf[1][ks], kf, sacc[1][nt], 0,0,0);
        }
      // ---- causal mask (only the diagonal tiles need it) ----
      if (kt >= 2*qt) {
        #pragma unroll
        for (int mt = 0; mt < 2; mt++)
          #pragma unroll
          for (int nt = 0; nt < 4; nt++)
            #pragma unroll
            for (int r = 0; r < 4; r++)
              if (kb + nt*16 + l16 > qrow0 + mt*16 + quad*4 + r)
                sacc[mt][nt][r] = -1e30f;
      }
      // ---- online softmax ----
      float alpha[2][4];
      #pragma unroll
      for (int mt = 0; mt < 2; mt++)
        #pragma unroll
        for (int r = 0; r < 4; r++) {
          float mx = fmaxf(fmaxf(sacc[mt][0][r], sacc[mt][1][r]),
                           fmaxf(sacc[mt][2][r], sacc[mt][3][r]));
          mx = qmax16(mx);
          const float mnew = fmaxf(m_run[mt][r], mx);
          alpha[mt][r] = __expf(m_run[mt][r] - mnew);
          m_run[mt][r] = mnew;
        }
      #pragma unroll
      for (int mt = 0; mt < 2; mt++)
        #pragma unroll
        for (int r = 0; r < 4; r++) {
          float rs = 0.f;
          #pragma unroll
          for (int nt = 0; nt < 4; nt++) {
            const float p = __expf(sacc[mt][nt][r] - m_run[mt][r]);
            rs += p;
            Ps[wave][mt*16 + quad*4 + r][nt*16 + l16] = f2bf(p);  // C-layout write
          }
          rs = qsum16(rs);
          l_run[mt][r] = l_run[mt][r] * alpha[mt][r] + rs;
        }
      // Compiler fence: forbid hoisting the Ps vector loads above the scalar
      // Ps stores (TBAA). HW DS ops are in-order per wave [m120].
      asm volatile("" ::: "memory");
      #pragma unroll
      for (int mt = 0; mt < 2; mt++)
        #pragma unroll
        for (int nt = 0; nt < 4; nt++)
          #pragma unroll
          for (int r = 0; r < 4; r++)
            oacc[mt][nt][r] *= alpha[mt][r];
      // ---- O += P @ V  (P re-read in A-layout; wave-private LDS) ----
      #pragma unroll
      for (int ks = 0; ks < 2; ks++) {
        bf16x8 pf0 = *(const bf16x8*)&Ps[wave][l16][ks*32 + quad*8];
        bf16x8 pf1 = *(const bf16x8*)&Ps[wave][16 + l16][ks*32 + quad*8];
        #pragma unroll
        for (int nt = 0; nt < 4; nt++) {
          bf16x8 vf = *(const bf16x8*)&Vt[nt*16 + l16][ks*32 + quad*8];
          oacc[0][nt] = __builtin_amdgcn_mfma_f32_16x16x32_bf16(pf0, vf, oacc[0][nt], 0,0,0);
          oacc[1][nt] = __builtin_amdgcn_mfma_f32_16x16x32_bf16(pf1, vf, oacc[1][nt], 0,0,0);
        }
      }
    }
  }

  // ---- epilogue: O /= l, write [SEQ][2048] ----
  #pragma unroll
  for (int mt = 0; mt < 2; mt++)
    #pragma unroll
    for (int r = 0; r < 4; r++) {
      const float inv = 1.0f / l_run[mt][r];
      const int qrow = qrow0 + mt*16 + quad*4 + r;
      #pragma unroll
      for (int nt = 0; nt < 4; nt++)
        Ob[(size_t)qrow * QN + h*64 + nt*16 + l16] = f2bf(oacc[mt][nt][r] * inv);
    }
}

// ---------------------------------------------------------------------------
extern "C" void kernel_launch(void* const* d_in, const int* in_sizes, int n_in,
                              void* d_out, int out_size, void* d_ws, size_t ws_size,
                              hipStream_t stream) {
  const void* X    = d_in[0];
  const void* cosr = d_in[1];
  const void* sinr = d_in[2];
  const void* wq   = d_in[3];
  const void* wk   = d_in[4];
  const void* wv   = d_in[5];
  const void* wo   = d_in[6];

  char* ws = (char*)d_ws;
  const size_t MB = 1024u * 1024u;
  u16* Xc   = (u16*)(ws);                 // 8 MB
  u16* wqc  = (u16*)(ws + 8*MB);          // 8 MB (Ab aliases this later)
  u16* wkc  = (u16*)(ws + 16*MB);         // 2 MB
  u16* wvc  = (u16*)(ws + 18*MB);         // 2 MB
  u16* woc  = (u16*)(ws + 20*MB);         // 8 MB
  u16* cosc = (u16*)(ws + 28*MB);         // 256 KB
  u16* sinc = (u16*)(ws + 28*MB + 256*1024);  // 256 KB
  u16* Qb   = (u16*)(ws + 28*MB + 512*1024);  // 8 MB
  u16* Kb   = (u16*)(ws + 36*MB + 512*1024);  // 2 MB
  u16* Vb   = (u16*)(ws + 38*MB + 512*1024);  // 2 MB
  u16* Ab   = wqc;   // alias: wqc dead after first gemm; attn writes Ab after

  dim3 blk(256);
  conv_all<<<dim3(7296), blk, 0, stream>>>(X, cosr, sinr, wq, wk, wv, wo,
                                           Xc, cosc, sinc, wqc, wkc, wvc, woc);
  gemm_nt<<<dim3(16, 16), blk, 0, stream>>>(Xc, wqc, Qb, SEQ, QN,   DMODEL, nullptr);
  gemm_nt<<<dim3(4, 16),  blk, 0, stream>>>(Xc, wkc, Kb, SEQ, KVNN, DMODEL, nullptr);
  gemm_nt<<<dim3(4, 16),  blk, 0, stream>>>(Xc, wvc, Vb, SEQ, KVNN, DMODEL, nullptr);
  rope_kernel<<<dim3((SEQ*(NQH+NKVH)*32)/256), blk, 0, stream>>>(Qb, Kb, cosc, sinc);
  attn_kernel<<<dim3(NQH, SEQ/128), blk, 0, stream>>>(Qb, Kb, Vb, Ab);
  gemm_nt<<<dim3(16, 16), blk, 0, stream>>>(Ab, woc, d_out, SEQ, DMODEL, DMODEL,
                                            (const uint32_t*)cosr);
}

// Round 5
// 289.384 us; speedup vs baseline: 1.2999x; 1.2999x over previous
//
#include <hip/hip_runtime.h>
#include <stdint.h>

#define SEQ   2048
#define DMODEL 2048
#define NQH   32
#define NKVH  8
#define HDIM  64
#define QN    (NQH*HDIM)    // 2048
#define KVNN  (NKVH*HDIM)   // 512

typedef __bf16 bf16x8 __attribute__((ext_vector_type(8)));
typedef float  f32x4  __attribute__((ext_vector_type(4)));
typedef unsigned short u16;

__device__ __forceinline__ u16 f2bf(float f) {
  uint32_t u = __builtin_bit_cast(uint32_t, f);
  u += 0x7fffu + ((u >> 16) & 1u);   // RNE
  return (u16)(u >> 16);
}
__device__ __forceinline__ float bf2f(u16 b) {
  return __builtin_bit_cast(float, (uint32_t)b << 16);
}
__device__ __forceinline__ bool probe_is_f32(const uint32_t* p) {
  return (p[0] & 0xFFFFu) == 0u;   // cos[0]=1.0: f32->0x3F800000, bf16 pair->0x3F803F80
}

// ---------------------------------------------------------------------------
// Fused input conversion: all 7 inputs -> bf16 copies in ws (8 elts/thread).
// ---------------------------------------------------------------------------
__global__ __launch_bounds__(256)
void conv_all(const void* __restrict__ X, const void* __restrict__ cosv,
              const void* __restrict__ sinv, const void* __restrict__ wq,
              const void* __restrict__ wk, const void* __restrict__ wv,
              const void* __restrict__ wo,
              u16* __restrict__ Xc, u16* __restrict__ cosc, u16* __restrict__ sinc,
              u16* __restrict__ wqc, u16* __restrict__ wkc, u16* __restrict__ wvc,
              u16* __restrict__ woc)
{
  const bool f32in = probe_is_f32((const uint32_t*)cosv);
  const long t = (long)blockIdx.x * 256 + threadIdx.x;
  const void* src; u16* dst; long off;
  if      (t < 524288L)  { src = X;    dst = Xc;   off = t; }
  else if (t < 1048576L) { src = wq;   dst = wqc;  off = t - 524288L; }
  else if (t < 1179648L) { src = wk;   dst = wkc;  off = t - 1048576L; }
  else if (t < 1310720L) { src = wv;   dst = wvc;  off = t - 1179648L; }
  else if (t < 1835008L) { src = wo;   dst = woc;  off = t - 1310720L; }
  else if (t < 1851392L) { src = cosv; dst = cosc; off = t - 1835008L; }
  else                   { src = sinv; dst = sinc; off = t - 1851392L; }
  if (f32in) {
    const float4* s = (const float4*)src;
    float4 a = s[2*off], b = s[2*off + 1];
    union { u16 h[8]; uint4 u; } o;
    o.h[0]=f2bf(a.x); o.h[1]=f2bf(a.y); o.h[2]=f2bf(a.z); o.h[3]=f2bf(a.w);
    o.h[4]=f2bf(b.x); o.h[5]=f2bf(b.y); o.h[6]=f2bf(b.z); o.h[7]=f2bf(b.w);
    *(uint4*)(dst + off*8) = o.u;
  } else {
    *(uint4*)(dst + off*8) = ((const uint4*)src)[off];
  }
}

// ---------------------------------------------------------------------------
// Merged QKV projection: C = X @ [Wq;Wk;Wv]^T over N=3072, 128x128 tiles.
// Per-block remap of weight source and output destination (wave-uniform).
// ---------------------------------------------------------------------------
__global__ __launch_bounds__(256, 2)
void gemm_qkv(const u16* __restrict__ A,
              const u16* __restrict__ wq, const u16* __restrict__ wk,
              const u16* __restrict__ wv,
              u16* __restrict__ Qb, u16* __restrict__ Kb, u16* __restrict__ Vb)
{
  __shared__ __align__(16) u16 As[128][40];
  __shared__ __align__(16) u16 Bs[128][40];
  const int tid  = threadIdx.x;
  const int wave = tid >> 6;
  const int lane = tid & 63;
  const int quad = lane >> 4;
  const int l16  = lane & 15;
  const int m0 = blockIdx.y * 128;
  const int n0 = blockIdx.x * 128;       // 0..2944
  const int wm = (wave >> 1) * 64;
  const int wn = (wave & 1) * 64;
  const int srow = tid >> 2;
  const int scol = (tid & 3) * 8;
  const int K = DMODEL;

  const u16* Bbase; u16* Cbase; int Cstride, nc0;
  if (n0 < 2048)      { Bbase = wq + (size_t)n0 * K;          Cbase = Qb; Cstride = QN;   nc0 = n0; }
  else if (n0 < 2560) { Bbase = wk + (size_t)(n0 - 2048) * K; Cbase = Kb; Cstride = KVNN; nc0 = n0 - 2048; }
  else                { Bbase = wv + (size_t)(n0 - 2560) * K; Cbase = Vb; Cstride = KVNN; nc0 = n0 - 2560; }

  f32x4 acc[4][4];
  #pragma unroll
  for (int i = 0; i < 4; i++)
    #pragma unroll
    for (int j = 0; j < 4; j++)
      acc[i][j] = (f32x4){0.f, 0.f, 0.f, 0.f};

  for (int k0 = 0; k0 < K; k0 += 32) {
    uint4 a0 = *(const uint4*)(A + (size_t)(m0 + srow)      * K + k0 + scol);
    uint4 a1 = *(const uint4*)(A + (size_t)(m0 + srow + 64) * K + k0 + scol);
    uint4 b0 = *(const uint4*)(Bbase + (size_t)(srow)      * K + k0 + scol);
    uint4 b1 = *(const uint4*)(Bbase + (size_t)(srow + 64) * K + k0 + scol);
    __syncthreads();
    *(uint4*)&As[srow][scol]      = a0;
    *(uint4*)&As[srow + 64][scol] = a1;
    *(uint4*)&Bs[srow][scol]      = b0;
    *(uint4*)&Bs[srow + 64][scol] = b1;
    __syncthreads();
    bf16x8 af[4], bfr[4];
    #pragma unroll
    for (int i = 0; i < 4; i++) af[i]  = *(const bf16x8*)&As[wm + i*16 + l16][quad*8];
    #pragma unroll
    for (int j = 0; j < 4; j++) bfr[j] = *(const bf16x8*)&Bs[wn + j*16 + l16][quad*8];
    #pragma unroll
    for (int i = 0; i < 4; i++)
      #pragma unroll
      for (int j = 0; j < 4; j++)
        acc[i][j] = __builtin_amdgcn_mfma_f32_16x16x32_bf16(af[i], bfr[j], acc[i][j], 0, 0, 0);
  }

  #pragma unroll
  for (int i = 0; i < 4; i++) {
    const int rb = m0 + wm + i*16 + quad*4;
    #pragma unroll
    for (int j = 0; j < 4; j++) {
      const int col = nc0 + wn + j*16 + l16;
      #pragma unroll
      for (int r = 0; r < 4; r++)
        Cbase[(size_t)(rb + r) * Cstride + col] = f2bf(acc[i][j][r]);
    }
  }
}

// ---------------------------------------------------------------------------
// C[M][N] = A[M][K] @ B[N][K]^T (O-projection). f32 or bf16 output per probe.
// ---------------------------------------------------------------------------
__global__ __launch_bounds__(256, 2)
void gemm_nt(const u16* __restrict__ A, const u16* __restrict__ B,
             void* __restrict__ C, int M, int N, int K,
             const uint32_t* outprobe)
{
  __shared__ __align__(16) u16 As[128][40];
  __shared__ __align__(16) u16 Bs[128][40];
  const int tid  = threadIdx.x;
  const int wave = tid >> 6;
  const int lane = tid & 63;
  const int quad = lane >> 4;
  const int l16  = lane & 15;
  const int m0 = blockIdx.y * 128;
  const int n0 = blockIdx.x * 128;
  const int wm = (wave >> 1) * 64;
  const int wn = (wave & 1) * 64;
  const int srow = tid >> 2;
  const int scol = (tid & 3) * 8;

  f32x4 acc[4][4];
  #pragma unroll
  for (int i = 0; i < 4; i++)
    #pragma unroll
    for (int j = 0; j < 4; j++)
      acc[i][j] = (f32x4){0.f, 0.f, 0.f, 0.f};

  for (int k0 = 0; k0 < K; k0 += 32) {
    uint4 a0 = *(const uint4*)(A + (size_t)(m0 + srow)      * K + k0 + scol);
    uint4 a1 = *(const uint4*)(A + (size_t)(m0 + srow + 64) * K + k0 + scol);
    uint4 b0 = *(const uint4*)(B + (size_t)(n0 + srow)      * K + k0 + scol);
    uint4 b1 = *(const uint4*)(B + (size_t)(n0 + srow + 64) * K + k0 + scol);
    __syncthreads();
    *(uint4*)&As[srow][scol]      = a0;
    *(uint4*)&As[srow + 64][scol] = a1;
    *(uint4*)&Bs[srow][scol]      = b0;
    *(uint4*)&Bs[srow + 64][scol] = b1;
    __syncthreads();
    bf16x8 af[4], bfr[4];
    #pragma unroll
    for (int i = 0; i < 4; i++) af[i]  = *(const bf16x8*)&As[wm + i*16 + l16][quad*8];
    #pragma unroll
    for (int j = 0; j < 4; j++) bfr[j] = *(const bf16x8*)&Bs[wn + j*16 + l16][quad*8];
    #pragma unroll
    for (int i = 0; i < 4; i++)
      #pragma unroll
      for (int j = 0; j < 4; j++)
        acc[i][j] = __builtin_amdgcn_mfma_f32_16x16x32_bf16(af[i], bfr[j], acc[i][j], 0, 0, 0);
  }

  const bool f32out = (outprobe != nullptr) && probe_is_f32(outprobe);
  #pragma unroll
  for (int i = 0; i < 4; i++) {
    const int rb = m0 + wm + i*16 + quad*4;
    #pragma unroll
    for (int j = 0; j < 4; j++) {
      const int col = n0 + wn + j*16 + l16;
      if (f32out) {
        float* Cf = (float*)C;
        #pragma unroll
        for (int r = 0; r < 4; r++)
          Cf[(size_t)(rb + r) * N + col] = acc[i][j][r];
      } else {
        u16* Ch = (u16*)C;
        #pragma unroll
        for (int r = 0; r < 4; r++)
          Ch[(size_t)(rb + r) * N + col] = f2bf(acc[i][j][r]);
      }
    }
  }
}

// ---------------------------------------------------------------------------
// RoPE in-place on Q [SEQ][2048] and K [SEQ][512]; Q additionally scaled 1/8.
// ---------------------------------------------------------------------------
__global__ void rope_kernel(u16* __restrict__ Qb, u16* __restrict__ Kb,
                            const u16* __restrict__ cosb, const u16* __restrict__ sinb)
{
  const int idx = blockIdx.x * 256 + threadIdx.x;
  const int qtotal = SEQ * NQH * 32;
  u16* base;
  int s, d;
  float scale;
  if (idx < qtotal) {
    s = idx >> 10;
    const int rem = idx & 1023;
    base = Qb + (size_t)s * QN + (rem >> 5) * 64;
    d = rem & 31;
    scale = 0.125f;
  } else {
    const int t = idx - qtotal;
    s = t >> 8;
    const int rem = t & 255;
    base = Kb + (size_t)s * KVNN + (rem >> 5) * 64;
    d = rem & 31;
    scale = 1.0f;
  }
  const float x1 = bf2f(base[d]);
  const float x2 = bf2f(base[d + 32]);
  const float c1 = bf2f(cosb[s * 64 + d]);
  const float c2 = bf2f(cosb[s * 64 + d + 32]);
  const float s1 = bf2f(sinb[s * 64 + d]);
  const float s2 = bf2f(sinb[s * 64 + d + 32]);
  base[d]      = f2bf((x1 * c1 - x2 * s1) * scale);
  base[d + 32] = f2bf((x2 * c2 + x1 * s2) * scale);
}

// ---------------------------------------------------------------------------
// Causal GQA flash attention, v2. Block = (head, 64-row Q tile): grid 32x32 =
// 1024 blocks (4/CU resident vs 2 before). Wave owns 16 Q rows. K-tile = 64.
// V^T stored XOR-swizzled: (d,key) at Vt[d][key ^ ((d>>3)*8)] -> conflict-free
// scalar transpose writes (was 16-way), uniform b128 reads.
// ---------------------------------------------------------------------------
__device__ __forceinline__ float qmax16(float v) {
  v = fmaxf(v, __shfl_xor(v, 1)); v = fmaxf(v, __shfl_xor(v, 2));
  v = fmaxf(v, __shfl_xor(v, 4)); v = fmaxf(v, __shfl_xor(v, 8));
  return v;
}
__device__ __forceinline__ float qsum16(float v) {
  v += __shfl_xor(v, 1); v += __shfl_xor(v, 2);
  v += __shfl_xor(v, 4); v += __shfl_xor(v, 8);
  return v;
}

__global__ __launch_bounds__(256, 4)
void attn_kernel(const u16* __restrict__ Qb,   // [SEQ][2048] RoPE'd, pre-scaled
                 const u16* __restrict__ Kb,   // [SEQ][512]  RoPE'd
                 const u16* __restrict__ Vb,   // [SEQ][512]
                 u16* __restrict__ Ob)         // [SEQ][2048]
{
  const int h   = blockIdx.x;       // 0..31
  const int qt  = blockIdx.y;       // 0..31 (64-row tiles)
  const int hkv = h >> 2;
  __shared__ __align__(16) u16 Ks[64][72];     // [key][d]
  __shared__ __align__(16) u16 Vt[64][72];     // [d][key ^ ((d>>3)*8)]
  __shared__ __align__(16) u16 Ps[4][16][72];  // per-wave P round-trip

  const int tid  = threadIdx.x;
  const int wave = tid >> 6;
  const int lane = tid & 63;
  const int quad = lane >> 4;
  const int l16  = lane & 15;
  const int qrow0 = qt * 64 + wave * 16;

  // Q A-frags (m = lane&15, k = quad*8+j)
  bf16x8 qf[2];
  #pragma unroll
  for (int ks = 0; ks < 2; ks++)
    qf[ks] = *(const bf16x8*)(Qb + (size_t)(qrow0 + l16) * QN + h*64 + ks*32 + quad*8);

  f32x4 oacc[4];
  #pragma unroll
  for (int nt = 0; nt < 4; nt++) oacc[nt] = (f32x4){0.f, 0.f, 0.f, 0.f};
  float m_run[4], l_run[4];
  #pragma unroll
  for (int r = 0; r < 4; r++) { m_run[r] = -1e30f; l_run[r] = 0.f; }

  const int sr = tid >> 3;          // 0..31 key
  const int sc = (tid & 7) * 8;     // d offset
  const int swz = (sc >> 3) * 8;    // == ((d>>3)*8) for d = sc+j, j<8
  const int ktmax = qt + 1;

  for (int kt = 0; kt < ktmax; kt++) {
    const int kb = kt * 64;
    union { uint4 u; u16 h[8]; } kv0, kv1, vv0, vv1;
    kv0.u = *(const uint4*)(Kb + (size_t)(kb + sr)      * KVNN + hkv*64 + sc);
    kv1.u = *(const uint4*)(Kb + (size_t)(kb + sr + 32) * KVNN + hkv*64 + sc);
    vv0.u = *(const uint4*)(Vb + (size_t)(kb + sr)      * KVNN + hkv*64 + sc);
    vv1.u = *(const uint4*)(Vb + (size_t)(kb + sr + 32) * KVNN + hkv*64 + sc);
    __syncthreads();
    *(uint4*)&Ks[sr][sc]      = kv0.u;
    *(uint4*)&Ks[sr + 32][sc] = kv1.u;
    #pragma unroll
    for (int j = 0; j < 8; j++) {
      Vt[sc + j][sr ^ swz]        = vv0.h[j];
      Vt[sc + j][(sr + 32) ^ swz] = vv1.h[j];
    }
    __syncthreads();

    const bool diag = (kt == qt);
    // ---- S = Q @ K^T (skip fully-masked nt tiles on the diagonal) ----
    f32x4 sacc[4];
    #pragma unroll
    for (int nt = 0; nt < 4; nt++) sacc[nt] = (f32x4){0.f, 0.f, 0.f, 0.f};
    #pragma unroll
    for (int ks = 0; ks < 2; ks++)
      #pragma unroll
      for (int nt = 0; nt < 4; nt++)
        if (!diag || nt <= wave) {
          bf16x8 kf = *(const bf16x8*)&Ks[nt*16 + l16][ks*32 + quad*8];
          sacc[nt] = __builtin_amdgcn_mfma_f32_16x16x32_bf16(qf[ks], kf, sacc[nt], 0, 0, 0);
        }
    // ---- causal mask (diagonal tile only) ----
    if (diag) {
      #pragma unroll
      for (int nt = 0; nt < 4; nt++)
        #pragma unroll
        for (int r = 0; r < 4; r++)
          if (kb + nt*16 + l16 > qrow0 + quad*4 + r)
            sacc[nt][r] = -1e30f;
    }
    // ---- online softmax ----
    float alpha[4];
    #pragma unroll
    for (int r = 0; r < 4; r++) {
      float mx = fmaxf(fmaxf(sacc[0][r], sacc[1][r]), fmaxf(sacc[2][r], sacc[3][r]));
      mx = qmax16(mx);
      const float mnew = fmaxf(m_run[r], mx);
      alpha[r] = __expf(m_run[r] - mnew);
      m_run[r] = mnew;
      float rs = 0.f;
      #pragma unroll
      for (int nt = 0; nt < 4; nt++) {
        const float p = __expf(sacc[nt][r] - mnew);
        rs += p;
        Ps[wave][quad*4 + r][nt*16 + l16] = f2bf(p);   // C-layout write
      }
      rs = qsum16(rs);
      l_run[r] = l_run[r] * alpha[r] + rs;
    }
    #pragma unroll
    for (int nt = 0; nt < 4; nt++)
      #pragma unroll
      for (int r = 0; r < 4; r++)
        oacc[nt][r] *= alpha[r];
    // fence: keep Ps vector loads below the scalar Ps stores (wave-private)
    asm volatile("" ::: "memory");
    // ---- O += P @ V (skip dead key-halves on the diagonal) ----
    #pragma unroll
    for (int ks = 0; ks < 2; ks++) {
      if (diag && wave < 2 && ks == 1) continue;  // keys 32..63 fully masked
      bf16x8 pf = *(const bf16x8*)&Ps[wave][l16][ks*32 + quad*8];
      #pragma unroll
      for (int nt = 0; nt < 4; nt++) {
        const int d = nt*16 + l16;
        bf16x8 vf = *(const bf16x8*)&Vt[d][(ks*32 + quad*8) ^ ((d >> 3) * 8)];
        oacc[nt] = __builtin_amdgcn_mfma_f32_16x16x32_bf16(pf, vf, oacc[nt], 0, 0, 0);
      }
    }
  }

  // ---- epilogue ----
  #pragma unroll
  for (int r = 0; r < 4; r++) {
    const float inv = 1.0f / l_run[r];
    const int qrow = qrow0 + quad*4 + r;
    #pragma unroll
    for (int nt = 0; nt < 4; nt++)
      Ob[(size_t)qrow * QN + h*64 + nt*16 + l16] = f2bf(oacc[nt][r] * inv);
  }
}

// ---------------------------------------------------------------------------
extern "C" void kernel_launch(void* const* d_in, const int* in_sizes, int n_in,
                              void* d_out, int out_size, void* d_ws, size_t ws_size,
                              hipStream_t stream) {
  const void* X    = d_in[0];
  const void* cosr = d_in[1];
  const void* sinr = d_in[2];
  const void* wq   = d_in[3];
  const void* wk   = d_in[4];
  const void* wv   = d_in[5];
  const void* wo   = d_in[6];

  char* ws = (char*)d_ws;
  const size_t MB = 1024u * 1024u;
  u16* Xc   = (u16*)(ws);                      // 8 MB
  u16* wqc  = (u16*)(ws + 8*MB);               // 8 MB (Ab aliases after QKV gemm)
  u16* wkc  = (u16*)(ws + 16*MB);              // 2 MB
  u16* wvc  = (u16*)(ws + 18*MB);              // 2 MB
  u16* woc  = (u16*)(ws + 20*MB);              // 8 MB
  u16* cosc = (u16*)(ws + 28*MB);              // 256 KB
  u16* sinc = (u16*)(ws + 28*MB + 256*1024);   // 256 KB
  u16* Qb   = (u16*)(ws + 28*MB + 512*1024);   // 8 MB
  u16* Kb   = (u16*)(ws + 36*MB + 512*1024);   // 2 MB
  u16* Vb   = (u16*)(ws + 38*MB + 512*1024);   // 2 MB
  u16* Ab   = wqc;   // wqc dead after gemm_qkv

  dim3 blk(256);
  conv_all<<<dim3(7296), blk, 0, stream>>>(X, cosr, sinr, wq, wk, wv, wo,
                                           Xc, cosc, sinc, wqc, wkc, wvc, woc);
  gemm_qkv<<<dim3(24, 16), blk, 0, stream>>>(Xc, wqc, wkc, wvc, Qb, Kb, Vb);
  rope_kernel<<<dim3((SEQ*(NQH+NKVH)*32)/256), blk, 0, stream>>>(Qb, Kb, cosc, sinc);
  attn_kernel<<<dim3(NQH, SEQ/64), blk, 0, stream>>>(Qb, Kb, Vb, Ab);
  gemm_nt<<<dim3(16, 16), blk, 0, stream>>>(Ab, woc, d_out, SEQ, DMODEL, DMODEL,
                                            (const uint32_t*)cosr);
}